// Round 1
// 840.368 us; speedup vs baseline: 1.0461x; 1.0461x over previous
//
#include <hip/hip_runtime.h>
#include <math.h>

// Merton jump diffusion path simulation.
// out[p][0] = S0; out[p][s+1] = S0 * exp( sum_{k<=s} log_ret[k][p] )
//
// R2: LDS-staged coalesced stores (kept).
// R3: occupancy was 5.5% (one lane per path -> 512 waves total; latency-bound,
//     23% HBM, 15% VALU). Parallelize the time axis: 16 waves per 64-path block,
//     each wave owns an 8-step chunk of a 128-step tile. Chunk log-returns stay
//     in registers (inputs still read exactly once); chunk sums go through an
//     LDS block-scan to produce each wave's cumsum prefix. 16x wave count.

#define N_STEPS 2048
#define N_PATHS 32768
#define ROW (N_STEPS + 1)

#define NWAVES 16
#define SUB 8                      // steps per lane per tile
#define TILE_S (NWAVES * SUB)      // 128
#define NTILES (N_STEPS / TILE_S)  // 16

#define DT_F 0.00048828125f                 // 1/2048 exact
#define C_DIFF_F 0.004419417382415922f      // SIGMA * sqrt(DT)
#define KAPPA_F 0.046027859908717f          // exp(0.045) - 1
#define ND_F (-4.8828125e-6f)               // -0.01 * DT

__global__ __launch_bounds__(1024, 4) void merton_paths_kernel(
    const float* __restrict__ S0,
    const float* __restrict__ z_diff,
    const float* __restrict__ z_jump,
    const int* __restrict__ n_jumps,
    float* __restrict__ out) {
    const int tid  = threadIdx.x;
    const int lane = tid & 63;
    const int w    = tid >> 6;               // wave id 0..15 = time-chunk id
    const int pbase = blockIdx.x * 64;
    const int p     = pbase + lane;
    const float s0  = S0[0];

    // staging tile [path][step]; stride 129 words -> lane-stride 1 bank (free)
    __shared__ float stage[64][TILE_S + 1];
    __shared__ float ws[NWAVES][64];         // per-wave chunk sums, [w][path-lane]

    const float r = __expf(ND_F);            // per-step lambda decay factor

    if (w == 0) out[(size_t)p * ROW] = s0;

    // per-lane pointers at (step = w*SUB, path = p); step-major layout
    const float* zd_p = z_diff  + (size_t)(w * SUB) * N_PATHS + p;
    const float* zj_p = z_jump  + (size_t)(w * SUB) * N_PATHS + p;
    const int*   nj_p = n_jumps + (size_t)(w * SUB) * N_PATHS + p;

    float carry = 0.0f;                      // cumsum through all previous tiles

    for (int t = 0; t < NTILES; ++t) {
        // ---- phase A: load my 8 (step,path) triples, local cumsum in regs ----
        float zd[SUB], zj[SUB];
        int   nj[SUB];
#pragma unroll
        for (int i = 0; i < SUB; ++i) {
            size_t off = (size_t)i * N_PATHS;
            zd[i] = zd_p[off];
            zj[i] = zj_p[off];
            nj[i] = nj_p[off];
        }
        // fresh lambda exponent each tile (1 transcendental per 8 steps)
        float e = __expf(ND_F * (float)(t * TILE_S + w * SUB));
        float c[SUB];
        float acc = 0.0f;
#pragma unroll
        for (int i = 0; i < SUB; ++i) {
            float lam = 0.1f + 0.9f * e;
            e *= r;
            float drift = -(lam * KAPPA_F) * DT_F;
            float njf = (float)nj[i];
            float val = (drift + C_DIFF_F * zd[i]) + sqrtf(njf) * 0.3f * zj[i];
            acc += val;
            c[i] = acc;                      // local (within-chunk) cumsum
        }
        ws[w][lane] = acc;
        __syncthreads();

        // ---- phase B: block scan of the 16 chunk sums for my path ----
        float pre = carry;                   // exclusive prefix for my chunk
        float tot = 0.0f;
#pragma unroll
        for (int ww = 0; ww < NWAVES; ++ww) {
            float v = ws[ww][lane];
            pre += (ww < w) ? v : 0.0f;
            tot += v;
        }
        carry += tot;

        // ---- phase C: exp + stage ----
#pragma unroll
        for (int i = 0; i < SUB; ++i) {
            stage[lane][w * SUB + i] = s0 * __expf(pre + c[i]);
        }
        __syncthreads();

        // ---- phase D: drain; 4 rows/wave, 2 halves -> 256B coalesced stores ----
        {
            float* obase = out + (size_t)pbase * ROW + 1 + t * TILE_S;
#pragma unroll
            for (int k = 0; k < 4; ++k) {
                int rr = w * 4 + k;
                float* orow = obase + (size_t)rr * ROW;
                orow[lane]      = stage[rr][lane];
                orow[lane + 64] = stage[rr][lane + 64];
            }
        }
        __syncthreads();

        zd_p += (size_t)TILE_S * N_PATHS;
        zj_p += (size_t)TILE_S * N_PATHS;
        nj_p += (size_t)TILE_S * N_PATHS;
    }
}

extern "C" void kernel_launch(void* const* d_in, const int* in_sizes, int n_in,
                              void* d_out, int out_size, void* d_ws, size_t ws_size,
                              hipStream_t stream) {
    const float* S0      = (const float*)d_in[0];
    const float* z_diff  = (const float*)d_in[1];
    const float* z_jump  = (const float*)d_in[2];
    const int*   n_jumps = (const int*)d_in[3];
    float* out = (float*)d_out;

    dim3 block(1024);
    dim3 grid(N_PATHS / 64);   // 512 blocks x 16 waves = 8192 waves
    hipLaunchKernelGGL(merton_paths_kernel, grid, block, 0, stream,
                       S0, z_diff, z_jump, n_jumps, out);
}